// Round 1
// baseline (92.639 us; speedup 1.0000x reference)
//
#include <hip/hip_runtime.h>
#include <hip/hip_bf16.h>
#include <math.h>

// Problem constants (fixed by setup_inputs)
#define BB 2
#define NN 4096
#define MM 4096
#define DD 64

#define BN 64          // source rows per block tile
#define BM 64          // target cols per M tile
#define NSPLIT 4       // M-dimension split across blockIdx.y
#define MRANGE (MM / NSPLIT)      // 1024
#define NTILES_N (NN / BN)        // 64
#define LDF 68         // padded LDS stride in floats (16B aligned rows, low bank conflict)

// ---------------------------------------------------------------------------
// Kernel 1: L2-normalize feature rows (one 64-lane wave per row, D == 64)
// ---------------------------------------------------------------------------
__global__ __launch_bounds__(256) void norm_kernel(const float* __restrict__ fs,
                                                   const float* __restrict__ ft,
                                                   float* __restrict__ fsn,
                                                   float* __restrict__ ftn) {
    int row  = blockIdx.x * 4 + (threadIdx.x >> 6);   // 4 waves per block
    int lane = threadIdx.x & 63;
    const float* src;
    float* dst;
    int r;
    if (row < BB * NN) { src = fs; dst = fsn; r = row; }
    else               { src = ft; dst = ftn; r = row - BB * NN; }
    float x = src[(size_t)r * DD + lane];
    float s = x * x;
    #pragma unroll
    for (int o = 32; o > 0; o >>= 1) s += __shfl_xor(s, o, 64);
    dst[(size_t)r * DD + lane] = x / sqrtf(s);
}

// ---------------------------------------------------------------------------
// Kernel 2: pair kernel. Block = 64 rows x (MRANGE cols, tiled by 64).
// 256 threads as 16x16, each computes a 4x4 micro-tile (rows ty+16i, cols tx+16j).
// Writes per-split partial (Kx,Ky,Kz,Ksum) per row to ws.
// ---------------------------------------------------------------------------
__global__ __launch_bounds__(256) void flow_kernel(const float* __restrict__ fsn,
                                                   const float* __restrict__ ftn,
                                                   const float* __restrict__ cs,
                                                   const float* __restrict__ ct,
                                                   const float* __restrict__ eps,
                                                   float* __restrict__ part) {
    __shared__ float fsl[BN * LDF];
    __shared__ float ftl[BM * LDF];
    __shared__ float scx[BN], scy[BN], scz[BN], ssq[BN];
    __shared__ float tcx[BM], tcy[BM], tcz[BM], tsq[BM];

    const int t  = threadIdx.x;
    const int tx = t & 15;
    const int ty = t >> 4;
    const int bidx  = blockIdx.x;       // 0 .. BB*NTILES_N-1
    const int split = blockIdx.y;       // 0 .. NSPLIT-1
    const int b  = bidx / NTILES_N;
    const int n0 = (bidx % NTILES_N) * BN;

    const float invtau = 1.0f / (__expf(eps[0]) + 0.03f);

    // stage source-feature tile (rows n0..n0+63), transposed-free row-major
    {
        const float4* g = (const float4*)(fsn + ((size_t)b * NN + n0) * DD);
        #pragma unroll
        for (int k = 0; k < 4; ++k) {
            int idx = t + k * 256;          // 1024 float4 total
            int r = idx >> 4, q = idx & 15;
            float4 v = g[r * 16 + q];
            *(float4*)&fsl[r * LDF + q * 4] = v;
        }
        if (t < BN) {
            const float* c = cs + ((size_t)b * NN + n0 + t) * 3;
            float x = c[0], y = c[1], z = c[2];
            scx[t] = x; scy[t] = y; scz[t] = z;
            ssq[t] = x * x + y * y + z * z;
        }
    }

    float accx[4] = {0.f, 0.f, 0.f, 0.f};
    float accy[4] = {0.f, 0.f, 0.f, 0.f};
    float accz[4] = {0.f, 0.f, 0.f, 0.f};
    float accw[4] = {0.f, 0.f, 0.f, 0.f};

    for (int mt = 0; mt < MRANGE / BM; ++mt) {
        const int m0 = split * MRANGE + mt * BM;
        __syncthreads();   // protect previous iteration's LDS reads (and first fs staging)
        {
            const float4* g = (const float4*)(ftn + ((size_t)b * MM + m0) * DD);
            #pragma unroll
            for (int k = 0; k < 4; ++k) {
                int idx = t + k * 256;
                int r = idx >> 4, q = idx & 15;
                float4 v = g[r * 16 + q];
                *(float4*)&ftl[r * LDF + q * 4] = v;
            }
            if (t < BM) {
                const float* c = ct + ((size_t)b * MM + m0 + t) * 3;
                float x = c[0], y = c[1], z = c[2];
                tcx[t] = x; tcy[t] = y; tcz[t] = z;
                tsq[t] = x * x + y * y + z * z;
            }
        }
        __syncthreads();

        // 4x4 dot products over D=64
        float dot[4][4];
        #pragma unroll
        for (int i = 0; i < 4; ++i)
            #pragma unroll
            for (int j = 0; j < 4; ++j) dot[i][j] = 0.f;

        #pragma unroll
        for (int d0 = 0; d0 < DD; d0 += 4) {
            float4 a[4], bv[4];
            #pragma unroll
            for (int i = 0; i < 4; ++i)
                a[i] = *(const float4*)&fsl[(ty + 16 * i) * LDF + d0];
            #pragma unroll
            for (int j = 0; j < 4; ++j)
                bv[j] = *(const float4*)&ftl[(tx + 16 * j) * LDF + d0];
            #pragma unroll
            for (int i = 0; i < 4; ++i)
                #pragma unroll
                for (int j = 0; j < 4; ++j) {
                    dot[i][j] = fmaf(a[i].x, bv[j].x, dot[i][j]);
                    dot[i][j] = fmaf(a[i].y, bv[j].y, dot[i][j]);
                    dot[i][j] = fmaf(a[i].z, bv[j].z, dot[i][j]);
                    dot[i][j] = fmaf(a[i].w, bv[j].w, dot[i][j]);
                }
        }

        // epilogue: support mask, exp kernel, accumulate
        #pragma unroll
        for (int i = 0; i < 4; ++i) {
            const int r = ty + 16 * i;
            const float sx = scx[r], sy = scy[r], sz = scz[r], ss = ssq[r];
            #pragma unroll
            for (int j = 0; j < 4; ++j) {
                const int c = tx + 16 * j;
                const float cx = tcx[c], cy = tcy[c], cz = tcz[c];
                const float st = sx * cx + sy * cy + sz * cz;
                const float d2 = (ss + tsq[c]) - 2.0f * st;
                const float Cf = 2.0f - 2.0f * dot[i][j];
                float w = __expf(-Cf * invtau);
                w = (d2 < 100.0f) ? w : 0.0f;
                accx[i] = fmaf(w, cx, accx[i]);
                accy[i] = fmaf(w, cy, accy[i]);
                accz[i] = fmaf(w, cz, accz[i]);
                accw[i] += w;
            }
        }
    }

    // reduce the 4 per-row stats across the 16 tx lanes (contiguous 16-lane groups)
    #pragma unroll
    for (int i = 0; i < 4; ++i) {
        #pragma unroll
        for (int o = 8; o > 0; o >>= 1) {
            accx[i] += __shfl_xor(accx[i], o, 16);
            accy[i] += __shfl_xor(accy[i], o, 16);
            accz[i] += __shfl_xor(accz[i], o, 16);
            accw[i] += __shfl_xor(accw[i], o, 16);
        }
    }
    if (tx == 0) {
        #pragma unroll
        for (int i = 0; i < 4; ++i) {
            const int r = n0 + ty + 16 * i;
            float4 v = make_float4(accx[i], accy[i], accz[i], accw[i]);
            *(float4*)&part[(((size_t)split * BB + b) * NN + r) * 4] = v;
        }
    }
}

// ---------------------------------------------------------------------------
// Kernel 3: combine splits, normalize, subtract coor_s
// ---------------------------------------------------------------------------
__global__ __launch_bounds__(256) void finish_kernel(const float* __restrict__ part,
                                                     const float* __restrict__ cs,
                                                     float* __restrict__ out) {
    int idx = blockIdx.x * 256 + threadIdx.x;   // b*NN + n
    if (idx >= BB * NN) return;
    float x = 0.f, y = 0.f, z = 0.f, w = 0.f;
    #pragma unroll
    for (int s = 0; s < NSPLIT; ++s) {
        const float4 v = *(const float4*)&part[((size_t)s * BB * NN + idx) * 4];
        x += v.x; y += v.y; z += v.z; w += v.w;
    }
    const float den = w + 1e-8f;
    out[(size_t)idx * 3 + 0] = x / den - cs[(size_t)idx * 3 + 0];
    out[(size_t)idx * 3 + 1] = y / den - cs[(size_t)idx * 3 + 1];
    out[(size_t)idx * 3 + 2] = z / den - cs[(size_t)idx * 3 + 2];
}

extern "C" void kernel_launch(void* const* d_in, const int* in_sizes, int n_in,
                              void* d_out, int out_size, void* d_ws, size_t ws_size,
                              hipStream_t stream) {
    const float* feat_s = (const float*)d_in[0];
    const float* feat_t = (const float*)d_in[1];
    const float* coor_s = (const float*)d_in[2];
    const float* coor_t = (const float*)d_in[3];
    const float* eps    = (const float*)d_in[4];
    float* out = (float*)d_out;

    float* ws  = (float*)d_ws;
    float* fsn  = ws;                                     // BB*NN*DD floats
    float* ftn  = ws + (size_t)BB * NN * DD;              // BB*MM*DD floats
    float* part = ws + 2 * (size_t)BB * NN * DD;          // NSPLIT*BB*NN*4 floats

    // 1) normalize features: BB*(NN+MM) rows, 4 rows (waves) per block
    norm_kernel<<<(BB * (NN + MM)) / 4, 256, 0, stream>>>(feat_s, feat_t, fsn, ftn);

    // 2) pair kernel: (BB * N-tiles) x NSPLIT blocks
    flow_kernel<<<dim3(BB * NTILES_N, NSPLIT), 256, 0, stream>>>(fsn, ftn, coor_s, coor_t, eps, part);

    // 3) finish
    finish_kernel<<<(BB * NN + 255) / 256, 256, 0, stream>>>(part, coor_s, out);
}

// Round 2
// 80.653 us; speedup vs baseline: 1.1486x; 1.1486x over previous
//
#include <hip/hip_runtime.h>
#include <hip/hip_bf16.h>
#include <math.h>

// Problem constants (fixed by setup_inputs)
#define BB 2
#define NN 4096
#define MM 4096
#define DD 64

#define BN 128         // source rows per block tile
#define BM 128         // target cols per M tile
#define NSPLIT 8       // M-dimension split across blockIdx.y
#define MRANGE (MM / NSPLIT)      // 512
#define NTILES_N (NN / BN)        // 32
#define LDF 68         // padded LDS stride in floats (16B-aligned rows, 2-way-max bank aliasing)

// ---------------------------------------------------------------------------
// Kernel 1: L2-normalize feature rows (one 64-lane wave per row, D == 64)
// ---------------------------------------------------------------------------
__global__ __launch_bounds__(256) void norm_kernel(const float* __restrict__ fs,
                                                   const float* __restrict__ ft,
                                                   float* __restrict__ fsn,
                                                   float* __restrict__ ftn) {
    int row  = blockIdx.x * 4 + (threadIdx.x >> 6);   // 4 waves per block
    int lane = threadIdx.x & 63;
    const float* src;
    float* dst;
    int r;
    if (row < BB * NN) { src = fs; dst = fsn; r = row; }
    else               { src = ft; dst = ftn; r = row - BB * NN; }
    float x = src[(size_t)r * DD + lane];
    float s = x * x;
    #pragma unroll
    for (int o = 32; o > 0; o >>= 1) s += __shfl_xor(s, o, 64);
    dst[(size_t)r * DD + lane] = x / sqrtf(s);
}

// ---------------------------------------------------------------------------
// Kernel 2: pair kernel. Block tile = 128 rows x 128 cols, 256 threads as
// 16x16, each computes an 8x8 register micro-tile (rows ty+16i, cols tx+16j).
// 2 FLOP per LDS byte. Writes per-split partial (Kx,Ky,Kz,Ksum) per row.
// ---------------------------------------------------------------------------
__global__ __launch_bounds__(256, 2) void flow_kernel(const float* __restrict__ fsn,
                                                      const float* __restrict__ ftn,
                                                      const float* __restrict__ cs,
                                                      const float* __restrict__ ct,
                                                      const float* __restrict__ eps,
                                                      float* __restrict__ part) {
    __shared__ float fsl[BN * LDF];
    __shared__ float ftl[BM * LDF];
    __shared__ float scx[BN], scy[BN], scz[BN], ssq[BN];
    __shared__ float tcx[BM], tcy[BM], tcz[BM], tsq[BM];

    const int t  = threadIdx.x;
    const int tx = t & 15;
    const int ty = t >> 4;
    const int bidx  = blockIdx.x;       // 0 .. BB*NTILES_N-1
    const int split = blockIdx.y;       // 0 .. NSPLIT-1
    const int b  = bidx / NTILES_N;
    const int n0 = (bidx % NTILES_N) * BN;

    const float invtau = 1.0f / (__expf(eps[0]) + 0.03f);

    // stage source-feature tile (rows n0..n0+127): 2048 float4, 8 per thread
    {
        const float4* g = (const float4*)(fsn + ((size_t)b * NN + n0) * DD);
        #pragma unroll
        for (int k = 0; k < 8; ++k) {
            int idx = t + k * 256;
            int r = idx >> 4, q = idx & 15;
            float4 v = g[r * 16 + q];
            *(float4*)&fsl[r * LDF + q * 4] = v;
        }
        if (t < BN) {
            const float* c = cs + ((size_t)b * NN + n0 + t) * 3;
            float x = c[0], y = c[1], z = c[2];
            scx[t] = x; scy[t] = y; scz[t] = z;
            ssq[t] = x * x + y * y + z * z;
        }
    }

    float accx[8], accy[8], accz[8], accw[8];
    #pragma unroll
    for (int i = 0; i < 8; ++i) { accx[i] = 0.f; accy[i] = 0.f; accz[i] = 0.f; accw[i] = 0.f; }

    for (int mt = 0; mt < MRANGE / BM; ++mt) {
        const int m0 = split * MRANGE + mt * BM;
        __syncthreads();   // protect previous iteration's LDS reads (and first fs staging)
        {
            const float4* g = (const float4*)(ftn + ((size_t)b * MM + m0) * DD);
            #pragma unroll
            for (int k = 0; k < 8; ++k) {
                int idx = t + k * 256;
                int r = idx >> 4, q = idx & 15;
                float4 v = g[r * 16 + q];
                *(float4*)&ftl[r * LDF + q * 4] = v;
            }
            if (t < BM) {
                const float* c = ct + ((size_t)b * MM + m0 + t) * 3;
                float x = c[0], y = c[1], z = c[2];
                tcx[t] = x; tcy[t] = y; tcz[t] = z;
                tsq[t] = x * x + y * y + z * z;
            }
        }
        __syncthreads();

        // 8x8 dot products over D=64
        float dot[8][8];
        #pragma unroll
        for (int i = 0; i < 8; ++i)
            #pragma unroll
            for (int j = 0; j < 8; ++j) dot[i][j] = 0.f;

        #pragma unroll 4
        for (int d0 = 0; d0 < DD; d0 += 4) {
            float4 a[8], bv[8];
            #pragma unroll
            for (int i = 0; i < 8; ++i)
                a[i] = *(const float4*)&fsl[(ty + 16 * i) * LDF + d0];
            #pragma unroll
            for (int j = 0; j < 8; ++j)
                bv[j] = *(const float4*)&ftl[(tx + 16 * j) * LDF + d0];
            #pragma unroll
            for (int i = 0; i < 8; ++i)
                #pragma unroll
                for (int j = 0; j < 8; ++j) {
                    dot[i][j] = fmaf(a[i].x, bv[j].x, dot[i][j]);
                    dot[i][j] = fmaf(a[i].y, bv[j].y, dot[i][j]);
                    dot[i][j] = fmaf(a[i].z, bv[j].z, dot[i][j]);
                    dot[i][j] = fmaf(a[i].w, bv[j].w, dot[i][j]);
                }
        }

        // epilogue: support mask, exp kernel, accumulate
        #pragma unroll
        for (int i = 0; i < 8; ++i) {
            const int r = ty + 16 * i;
            const float sx = scx[r], sy = scy[r], sz = scz[r], ss = ssq[r];
            #pragma unroll
            for (int j = 0; j < 8; ++j) {
                const int c = tx + 16 * j;
                const float cx = tcx[c], cy = tcy[c], cz = tcz[c];
                const float st = sx * cx + sy * cy + sz * cz;
                const float d2 = (ss + tsq[c]) - 2.0f * st;
                const float Cf = 2.0f - 2.0f * dot[i][j];
                float w = __expf(-Cf * invtau);
                w = (d2 < 100.0f) ? w : 0.0f;
                accx[i] = fmaf(w, cx, accx[i]);
                accy[i] = fmaf(w, cy, accy[i]);
                accz[i] = fmaf(w, cz, accz[i]);
                accw[i] += w;
            }
        }
    }

    // reduce the per-row stats across the 16 tx lanes (contiguous 16-lane groups)
    #pragma unroll
    for (int i = 0; i < 8; ++i) {
        #pragma unroll
        for (int o = 8; o > 0; o >>= 1) {
            accx[i] += __shfl_xor(accx[i], o, 16);
            accy[i] += __shfl_xor(accy[i], o, 16);
            accz[i] += __shfl_xor(accz[i], o, 16);
            accw[i] += __shfl_xor(accw[i], o, 16);
        }
    }
    if (tx == 0) {
        #pragma unroll
        for (int i = 0; i < 8; ++i) {
            const int r = n0 + ty + 16 * i;
            float4 v = make_float4(accx[i], accy[i], accz[i], accw[i]);
            *(float4*)&part[(((size_t)split * BB + b) * NN + r) * 4] = v;
        }
    }
}

// ---------------------------------------------------------------------------
// Kernel 3: combine splits, normalize, subtract coor_s
// ---------------------------------------------------------------------------
__global__ __launch_bounds__(256) void finish_kernel(const float* __restrict__ part,
                                                     const float* __restrict__ cs,
                                                     float* __restrict__ out) {
    int idx = blockIdx.x * 256 + threadIdx.x;   // b*NN + n
    if (idx >= BB * NN) return;
    float x = 0.f, y = 0.f, z = 0.f, w = 0.f;
    #pragma unroll
    for (int s = 0; s < NSPLIT; ++s) {
        const float4 v = *(const float4*)&part[((size_t)s * BB * NN + idx) * 4];
        x += v.x; y += v.y; z += v.z; w += v.w;
    }
    const float den = w + 1e-8f;
    out[(size_t)idx * 3 + 0] = x / den - cs[(size_t)idx * 3 + 0];
    out[(size_t)idx * 3 + 1] = y / den - cs[(size_t)idx * 3 + 1];
    out[(size_t)idx * 3 + 2] = z / den - cs[(size_t)idx * 3 + 2];
}

extern "C" void kernel_launch(void* const* d_in, const int* in_sizes, int n_in,
                              void* d_out, int out_size, void* d_ws, size_t ws_size,
                              hipStream_t stream) {
    const float* feat_s = (const float*)d_in[0];
    const float* feat_t = (const float*)d_in[1];
    const float* coor_s = (const float*)d_in[2];
    const float* coor_t = (const float*)d_in[3];
    const float* eps    = (const float*)d_in[4];
    float* out = (float*)d_out;

    float* ws  = (float*)d_ws;
    float* fsn  = ws;                                     // BB*NN*DD floats
    float* ftn  = ws + (size_t)BB * NN * DD;              // BB*MM*DD floats
    float* part = ws + 2 * (size_t)BB * NN * DD;          // NSPLIT*BB*NN*4 floats

    // 1) normalize features: BB*(NN+MM) rows, 4 rows (waves) per block
    norm_kernel<<<(BB * (NN + MM)) / 4, 256, 0, stream>>>(feat_s, feat_t, fsn, ftn);

    // 2) pair kernel: (BB * N-tiles) x NSPLIT blocks = 512 blocks (2/CU)
    flow_kernel<<<dim3(BB * NTILES_N, NSPLIT), 256, 0, stream>>>(fsn, ftn, coor_s, coor_t, eps, part);

    // 3) finish
    finish_kernel<<<(BB * NN + 255) / 256, 256, 0, stream>>>(part, coor_s, out);
}

// Round 3
// 42.674 us; speedup vs baseline: 2.1709x; 1.8900x over previous
//
#include <hip/hip_runtime.h>
#include <hip/hip_bf16.h>
#include <math.h>

// Problem constants (fixed by setup_inputs)
#define BB 2
#define NN 4096
#define MM 4096
#define DD 64

#define NSPLIT 8
#define MRANGE (MM / NSPLIT)   // 512 m per block
#define BMT 64                 // m per M-step
#define NSTEP (MRANGE / BMT)   // 8
#define BLK_N 64               // n rows per block (4 waves x 16)

typedef __attribute__((ext_vector_type(8))) short bf16x8;   // 8 bf16 (4 VGPRs)
typedef __attribute__((ext_vector_type(4))) float f32x4;

// ---------------------------------------------------------------------------
// Prep 1: L2-normalize features and emit [hi | lo] bf16 split, K=128 per row.
// dot(fs,ft) == hi_s.hi_t + lo_s.hi_t + hi_s.lo_t  (lo.lo ~ 1e-7, dropped)
// ---------------------------------------------------------------------------
__global__ __launch_bounds__(256) void prep_feat(const float* __restrict__ fs,
                                                 const float* __restrict__ ft,
                                                 unsigned short* __restrict__ fs2,
                                                 unsigned short* __restrict__ ft2) {
    int row  = blockIdx.x * 4 + (threadIdx.x >> 6);   // 4 waves per block
    int lane = threadIdx.x & 63;
    const float* src; unsigned short* dst; int r;
    if (row < BB * NN) { src = fs; dst = fs2; r = row; }
    else               { src = ft; dst = ft2; r = row - BB * NN; }
    float x = src[(size_t)r * DD + lane];
    float s = x * x;
    #pragma unroll
    for (int o = 32; o > 0; o >>= 1) s += __shfl_xor(s, o, 64);
    float xn = x / sqrtf(s);
    __hip_bfloat16 h = __float2bfloat16(xn);
    float hf = __bfloat162float(h);
    __hip_bfloat16 l = __float2bfloat16(xn - hf);
    dst[(size_t)r * 128 + lane]      = *(unsigned short*)&h;
    dst[(size_t)r * 128 + 64 + lane] = *(unsigned short*)&l;
}

// ---------------------------------------------------------------------------
// Prep 2: coordinate float4 tables {x, y, z, |c|^2}
// ---------------------------------------------------------------------------
__global__ __launch_bounds__(256) void prep_coord(const float* __restrict__ cs,
                                                  const float* __restrict__ ct,
                                                  float4* __restrict__ cs4,
                                                  float4* __restrict__ ct4) {
    int i = blockIdx.x * 256 + threadIdx.x;   // over BB*(NN+MM) points
    const float* c; float4* d;
    if (i < BB * NN) { c = cs + (size_t)i * 3; d = cs4 + i; }
    else { int r = i - BB * NN; c = ct + (size_t)r * 3; d = ct4 + r; }
    float x = c[0], y = c[1], z = c[2];
    *d = make_float4(x, y, z, x * x + y * y + z * z);
}

// ---------------------------------------------------------------------------
// Main: MFMA pair kernel.
// Block = 4 waves; wave owns 16 n-rows (A-frags + cs in registers, hoisted).
// Per M-step: stage 64 ft2 rows (16 KB, XOR-swizzled via pre-swizzled global
// source + linear global_load_lds dest), then 4 subtiles of 16 m:
//   6 MFMA (hi/lo split) -> C[r] = dot(n = n0w+4g+r, m = m0+st*16+(lane&15))
//   epilogue: f32 d2 mask + exp2 + register accumulate.
// ---------------------------------------------------------------------------
__global__ __launch_bounds__(256, 4) void flow_mfma(
    const unsigned short* __restrict__ fs2, const unsigned short* __restrict__ ft2,
    const float4* __restrict__ cs4, const float4* __restrict__ ct4,
    const float* __restrict__ eps, float4* __restrict__ part) {

    __shared__ unsigned short ftl[2][BMT * 128];   // 2 x 16 KB double buffer

    const int t    = threadIdx.x;
    const int lane = t & 63;
    const int w    = t >> 6;        // wave 0..3
    const int l15  = lane & 15;
    const int g    = lane >> 4;     // 16-lane group 0..3

    const int bidx  = blockIdx.x;   // 0..127
    const int split = blockIdx.y;   // 0..NSPLIT-1
    const int b   = bidx >> 6;                  // 64 n-blocks per batch
    const int n0w = (bidx & 63) * BLK_N + w * 16;
    const int m0s = split * MRANGE;

    // w = exp(-(2-2*dot)/tau) = exp2((dot-1)*k2)
    const float k2 = 2.0f * 1.44269504f / (__expf(eps[0]) + 0.03f);

    // Hoist A-fragments: wave's 16 fs2 rows, K=128 in 4 chunks of 32.
    // A layout (16x16x32): row = lane&15, k = (lane>>4)*8 + j within chunk.
    bf16x8 a[4];
    {
        const unsigned short* arow = fs2 + ((size_t)b * NN + n0w + l15) * 128;
        #pragma unroll
        for (int c = 0; c < 4; ++c)
            a[c] = *(const bf16x8*)(arow + c * 32 + g * 8);
    }
    // Hoist cs (n = n0w + 4g + r)
    float sx[4], sy[4], sz[4], sq[4];
    #pragma unroll
    for (int r = 0; r < 4; ++r) {
        float4 v = cs4[(size_t)b * NN + n0w + 4 * g + r];
        sx[r] = v.x; sy[r] = v.y; sz[r] = v.z; sq[r] = v.w;
    }

    float accx[4] = {0.f,0.f,0.f,0.f}, accy[4] = {0.f,0.f,0.f,0.f};
    float accz[4] = {0.f,0.f,0.f,0.f}, accw[4] = {0.f,0.f,0.f,0.f};

    // stage: 4 global_load_lds(16B) per wave; LDS dest linear, global source
    // pre-swizzled so a swizzled READ (slot ^= m&7) is conflict-free (rule 21).
    auto STAGE = [&](int buf, int step) {
        const int m0 = m0s + step * BMT;
        #pragma unroll
        for (int i = 0; i < 4; ++i) {
            int slot = w * 256 + i * 64 + lane;          // 16B slot in buffer
            int m    = slot >> 4;                        // row 0..63
            int scol = (slot & 15) ^ (m & 7);            // inverse swizzle on src
            const unsigned short* src = ft2 + ((size_t)b * MM + m0 + m) * 128 + scol * 8;
            unsigned short* dst = (unsigned short*)&ftl[buf][(size_t)(w * 256 + i * 64) * 8];
            __builtin_amdgcn_global_load_lds(
                (const __attribute__((address_space(1))) void*)src,
                (__attribute__((address_space(3))) void*)dst, 16, 0, 0);
        }
    };

    int cur = 0;
    STAGE(0, 0);

    for (int step = 0; step < NSTEP; ++step) {
        if (step + 1 < NSTEP) {
            STAGE(cur ^ 1, step + 1);
            asm volatile("s_waitcnt vmcnt(4)" ::: "memory");   // prev stage done, next in flight
        } else {
            asm volatile("s_waitcnt vmcnt(0)" ::: "memory");
        }
        __builtin_amdgcn_s_barrier();
        asm volatile("" ::: "memory");

        const int m0 = m0s + step * BMT;
        #pragma unroll
        for (int st = 0; st < 4; ++st) {
            const int mloc = st * 16 + l15;              // this lane's m column
            float4 cv = ct4[(size_t)b * MM + m0 + mloc]; // {x,y,z,|c|^2}

            // B-frags: col = lane&15 = m, k-chunk slot swizzled by row
            bf16x8 bf[4];
            #pragma unroll
            for (int c = 0; c < 4; ++c) {
                int slotswz = (c * 4 + g) ^ (mloc & 7);
                bf[c] = *(const bf16x8*)&ftl[cur][(size_t)mloc * 128 + slotswz * 8];
            }

            f32x4 C = {0.f, 0.f, 0.f, 0.f};
            // hi_s.hi_t
            C = __builtin_amdgcn_mfma_f32_16x16x32_bf16(a[0], bf[0], C, 0, 0, 0);
            C = __builtin_amdgcn_mfma_f32_16x16x32_bf16(a[1], bf[1], C, 0, 0, 0);
            // lo_s.hi_t
            C = __builtin_amdgcn_mfma_f32_16x16x32_bf16(a[2], bf[0], C, 0, 0, 0);
            C = __builtin_amdgcn_mfma_f32_16x16x32_bf16(a[3], bf[1], C, 0, 0, 0);
            // hi_s.lo_t
            C = __builtin_amdgcn_mfma_f32_16x16x32_bf16(a[0], bf[2], C, 0, 0, 0);
            C = __builtin_amdgcn_mfma_f32_16x16x32_bf16(a[1], bf[3], C, 0, 0, 0);

            #pragma unroll
            for (int r = 0; r < 4; ++r) {
                float st3 = sx[r] * cv.x + sy[r] * cv.y + sz[r] * cv.z;
                float d2  = sq[r] + cv.w - 2.0f * st3;
                float wgt = exp2f(C[r] * k2 - k2);
                wgt = (d2 < 100.0f) ? wgt : 0.0f;
                accx[r] = fmaf(wgt, cv.x, accx[r]);
                accy[r] = fmaf(wgt, cv.y, accy[r]);
                accz[r] = fmaf(wgt, cv.z, accz[r]);
                accw[r] += wgt;
            }
        }
        __builtin_amdgcn_s_barrier();
        asm volatile("" ::: "memory");
        cur ^= 1;
    }

    // reduce across the 16 lanes of each group (same n set, different m)
    #pragma unroll
    for (int r = 0; r < 4; ++r) {
        #pragma unroll
        for (int o = 1; o < 16; o <<= 1) {
            accx[r] += __shfl_xor(accx[r], o, 16);
            accy[r] += __shfl_xor(accy[r], o, 16);
            accz[r] += __shfl_xor(accz[r], o, 16);
            accw[r] += __shfl_xor(accw[r], o, 16);
        }
    }
    if (l15 == 0) {
        #pragma unroll
        for (int r = 0; r < 4; ++r) {
            int n = n0w + 4 * g + r;
            part[((size_t)split * BB + b) * NN + n] =
                make_float4(accx[r], accy[r], accz[r], accw[r]);
        }
    }
}

// ---------------------------------------------------------------------------
// Finish: combine splits, normalize, subtract coor_s
// ---------------------------------------------------------------------------
__global__ __launch_bounds__(256) void finish_kernel(const float4* __restrict__ part,
                                                     const float* __restrict__ cs,
                                                     float* __restrict__ out) {
    int idx = blockIdx.x * 256 + threadIdx.x;   // b*NN + n
    if (idx >= BB * NN) return;
    float x = 0.f, y = 0.f, z = 0.f, w = 0.f;
    #pragma unroll
    for (int s = 0; s < NSPLIT; ++s) {
        const float4 v = part[(size_t)s * BB * NN + idx];
        x += v.x; y += v.y; z += v.z; w += v.w;
    }
    const float den = w + 1e-8f;
    out[(size_t)idx * 3 + 0] = x / den - cs[(size_t)idx * 3 + 0];
    out[(size_t)idx * 3 + 1] = y / den - cs[(size_t)idx * 3 + 1];
    out[(size_t)idx * 3 + 2] = z / den - cs[(size_t)idx * 3 + 2];
}

extern "C" void kernel_launch(void* const* d_in, const int* in_sizes, int n_in,
                              void* d_out, int out_size, void* d_ws, size_t ws_size,
                              hipStream_t stream) {
    const float* feat_s = (const float*)d_in[0];
    const float* feat_t = (const float*)d_in[1];
    const float* coor_s = (const float*)d_in[2];
    const float* coor_t = (const float*)d_in[3];
    const float* eps    = (const float*)d_in[4];
    float* out = (float*)d_out;

    // workspace layout (bytes): fs2 2MB | ft2 2MB | cs4 128KB | ct4 128KB | part 1MB
    unsigned short* fs2 = (unsigned short*)d_ws;
    unsigned short* ft2 = fs2 + (size_t)BB * NN * 128;
    float4* cs4  = (float4*)(ft2 + (size_t)BB * MM * 128);
    float4* ct4  = cs4 + (size_t)BB * NN;
    float4* part = ct4 + (size_t)BB * MM;

    prep_feat<<<(BB * (NN + MM)) / 4, 256, 0, stream>>>(feat_s, feat_t, fs2, ft2);
    prep_coord<<<(BB * (NN + MM)) / 256, 256, 0, stream>>>(coor_s, coor_t, cs4, ct4);

    flow_mfma<<<dim3(BB * (NN / BLK_N), NSPLIT), 256, 0, stream>>>(
        fs2, ft2, cs4, ct4, eps, part);

    finish_kernel<<<(BB * NN + 255) / 256, 256, 0, stream>>>((const float4*)part, coor_s, out);
}

// Round 4
// 40.436 us; speedup vs baseline: 2.2910x; 1.0553x over previous
//
#include <hip/hip_runtime.h>
#include <hip/hip_bf16.h>
#include <math.h>

// Problem constants (fixed by setup_inputs)
#define BB 2
#define NN 4096
#define MM 4096
#define DD 64

#define NSPLIT 8
#define MRANGE (MM / NSPLIT)   // 512 m per block
#define BMT 64                 // m per M-step
#define NSTEP (MRANGE / BMT)   // 8
#define BLK_N 128              // n rows per block (4 waves x 32)
#define NBLK_B (NN / BLK_N)    // 32 n-blocks per batch

typedef __attribute__((ext_vector_type(8))) short bf16x8;   // 8 bf16 (4 VGPRs)
typedef __attribute__((ext_vector_type(4))) float f32x4;

#define FEAT_BLOCKS ((BB * (NN + MM)) / 4)    // 3072
#define COORD_BLOCKS ((BB * (NN + MM)) / 256) // 64

// ---------------------------------------------------------------------------
// Fused prep: (a) L2-normalize features, emit [hi|lo] bf16 split (K=128/row);
//             (b) coordinate float4 tables {x,y,z,|c|^2}.
// ---------------------------------------------------------------------------
__global__ __launch_bounds__(256) void prep_all(const float* __restrict__ fs,
                                                const float* __restrict__ ft,
                                                const float* __restrict__ cs,
                                                const float* __restrict__ ct,
                                                unsigned short* __restrict__ fs2,
                                                unsigned short* __restrict__ ft2,
                                                float4* __restrict__ cs4,
                                                float4* __restrict__ ct4) {
    int bid = blockIdx.x;
    if (bid < FEAT_BLOCKS) {
        int row  = bid * 4 + (threadIdx.x >> 6);   // 4 waves per block
        int lane = threadIdx.x & 63;
        const float* src; unsigned short* dst; int r;
        if (row < BB * NN) { src = fs; dst = fs2; r = row; }
        else               { src = ft; dst = ft2; r = row - BB * NN; }
        float x = src[(size_t)r * DD + lane];
        float s = x * x;
        #pragma unroll
        for (int o = 32; o > 0; o >>= 1) s += __shfl_xor(s, o, 64);
        float xn = x / sqrtf(s);
        __hip_bfloat16 h = __float2bfloat16(xn);
        float hf = __bfloat162float(h);
        __hip_bfloat16 l = __float2bfloat16(xn - hf);
        dst[(size_t)r * 128 + lane]      = *(unsigned short*)&h;
        dst[(size_t)r * 128 + 64 + lane] = *(unsigned short*)&l;
    } else {
        int i = (bid - FEAT_BLOCKS) * 256 + threadIdx.x;   // over BB*(NN+MM) pts
        const float* c; float4* d;
        if (i < BB * NN) { c = cs + (size_t)i * 3; d = cs4 + i; }
        else { int r = i - BB * NN; c = ct + (size_t)r * 3; d = ct4 + r; }
        float x = c[0], y = c[1], z = c[2];
        *d = make_float4(x, y, z, x * x + y * y + z * z);
    }
}

// ---------------------------------------------------------------------------
// Main: MFMA pair kernel.
// Block = 4 waves; wave owns 32 n-rows (two 16-row A-fragment sets + cs,
// hoisted to registers). Per M-step: stage 64 ft2 rows (16 KB, XOR-swizzled
// via pre-swizzled global source + linear global_load_lds dest, rule 21),
// then 4 subtiles of 16 m; each B-fragment set feeds TWO C tiles (12 MFMA):
//   C[r] = dot(n, m = m0+st*16+(lane&15)) ; epilogue: f32 d2 mask + exp2 +
//   register accumulate.
// ---------------------------------------------------------------------------
__global__ __launch_bounds__(256, 2) void flow_mfma(
    const unsigned short* __restrict__ fs2, const unsigned short* __restrict__ ft2,
    const float4* __restrict__ cs4, const float4* __restrict__ ct4,
    const float* __restrict__ eps, float4* __restrict__ part) {

    __shared__ unsigned short ftl[2][BMT * 128];   // 2 x 16 KB double buffer

    const int t    = threadIdx.x;
    const int lane = t & 63;
    const int w    = t >> 6;        // wave 0..3
    const int l15  = lane & 15;
    const int g    = lane >> 4;     // 16-lane group 0..3

    const int bidx  = blockIdx.x;   // 0 .. BB*NBLK_B-1 (64)
    const int split = blockIdx.y;   // 0 .. NSPLIT-1
    const int b   = bidx >> 5;      // NBLK_B = 32
    const int n0w = (bidx & 31) * BLK_N + w * 32;
    const int m0s = split * MRANGE;

    // w = exp(-(2-2*dot)/tau) = exp2((dot-1)*k2)
    const float k2 = 2.0f * 1.44269504f / (__expf(eps[0]) + 0.03f);

    // Hoist A-fragments: wave's 32 fs2 rows as two 16-row tiles, K=128 in 4
    // chunks of 32. A layout (16x16x32): row = lane&15, k-chunk slot = lane>>4.
    bf16x8 aA[4], aB[4];
    {
        const unsigned short* arowA = fs2 + ((size_t)b * NN + n0w + l15) * 128;
        const unsigned short* arowB = arowA + (size_t)16 * 128;
        #pragma unroll
        for (int c = 0; c < 4; ++c) {
            aA[c] = *(const bf16x8*)(arowA + c * 32 + g * 8);
            aB[c] = *(const bf16x8*)(arowB + c * 32 + g * 8);
        }
    }
    // Hoist cs: n = n0w + 16*h + 4g + r  ->  index h*4+r
    float sx[8], sy[8], sz[8], sq[8];
    #pragma unroll
    for (int h = 0; h < 2; ++h)
        #pragma unroll
        for (int r = 0; r < 4; ++r) {
            float4 v = cs4[(size_t)b * NN + n0w + 16 * h + 4 * g + r];
            sx[h * 4 + r] = v.x; sy[h * 4 + r] = v.y;
            sz[h * 4 + r] = v.z; sq[h * 4 + r] = v.w;
        }

    float accx[8], accy[8], accz[8], accw[8];
    #pragma unroll
    for (int i = 0; i < 8; ++i) { accx[i] = 0.f; accy[i] = 0.f; accz[i] = 0.f; accw[i] = 0.f; }

    // stage: 4 global_load_lds(16B) per wave; LDS dest linear, global source
    // pre-swizzled so a swizzled READ (slot ^= m&7) is conflict-free (rule 21).
    auto STAGE = [&](int buf, int step) {
        const int m0 = m0s + step * BMT;
        #pragma unroll
        for (int i = 0; i < 4; ++i) {
            int slot = w * 256 + i * 64 + lane;          // 16B slot in buffer
            int m    = slot >> 4;                        // row 0..63
            int scol = (slot & 15) ^ (m & 7);            // inverse swizzle on src
            const unsigned short* src = ft2 + ((size_t)b * MM + m0 + m) * 128 + scol * 8;
            unsigned short* dst = (unsigned short*)&ftl[buf][(size_t)(w * 256 + i * 64) * 8];
            __builtin_amdgcn_global_load_lds(
                (const __attribute__((address_space(1))) void*)src,
                (__attribute__((address_space(3))) void*)dst, 16, 0, 0);
        }
    };

    int cur = 0;
    STAGE(0, 0);

    for (int step = 0; step < NSTEP; ++step) {
        if (step + 1 < NSTEP) {
            STAGE(cur ^ 1, step + 1);
            asm volatile("s_waitcnt vmcnt(4)" ::: "memory");   // prev stage done, next in flight
        } else {
            asm volatile("s_waitcnt vmcnt(0)" ::: "memory");
        }
        __builtin_amdgcn_s_barrier();
        asm volatile("" ::: "memory");

        const int m0 = m0s + step * BMT;
        #pragma unroll
        for (int st = 0; st < 4; ++st) {
            const int mloc = st * 16 + l15;              // this lane's m column
            float4 cv = ct4[(size_t)b * MM + m0 + mloc]; // {x,y,z,|c|^2}

            // B-frags: col = lane&15 = m, k-chunk slot swizzled by row
            bf16x8 bf[4];
            #pragma unroll
            for (int c = 0; c < 4; ++c) {
                int slotswz = (c * 4 + g) ^ (mloc & 7);
                bf[c] = *(const bf16x8*)&ftl[cur][(size_t)mloc * 128 + slotswz * 8];
            }

            f32x4 CA = {0.f, 0.f, 0.f, 0.f};
            f32x4 CB = {0.f, 0.f, 0.f, 0.f};
            // hi_s.hi_t
            CA = __builtin_amdgcn_mfma_f32_16x16x32_bf16(aA[0], bf[0], CA, 0, 0, 0);
            CB = __builtin_amdgcn_mfma_f32_16x16x32_bf16(aB[0], bf[0], CB, 0, 0, 0);
            CA = __builtin_amdgcn_mfma_f32_16x16x32_bf16(aA[1], bf[1], CA, 0, 0, 0);
            CB = __builtin_amdgcn_mfma_f32_16x16x32_bf16(aB[1], bf[1], CB, 0, 0, 0);
            // lo_s.hi_t
            CA = __builtin_amdgcn_mfma_f32_16x16x32_bf16(aA[2], bf[0], CA, 0, 0, 0);
            CB = __builtin_amdgcn_mfma_f32_16x16x32_bf16(aB[2], bf[0], CB, 0, 0, 0);
            CA = __builtin_amdgcn_mfma_f32_16x16x32_bf16(aA[3], bf[1], CA, 0, 0, 0);
            CB = __builtin_amdgcn_mfma_f32_16x16x32_bf16(aB[3], bf[1], CB, 0, 0, 0);
            // hi_s.lo_t
            CA = __builtin_amdgcn_mfma_f32_16x16x32_bf16(aA[0], bf[2], CA, 0, 0, 0);
            CB = __builtin_amdgcn_mfma_f32_16x16x32_bf16(aB[0], bf[2], CB, 0, 0, 0);
            CA = __builtin_amdgcn_mfma_f32_16x16x32_bf16(aA[1], bf[3], CA, 0, 0, 0);
            CB = __builtin_amdgcn_mfma_f32_16x16x32_bf16(aB[1], bf[3], CB, 0, 0, 0);

            #pragma unroll
            for (int h = 0; h < 2; ++h) {
                #pragma unroll
                for (int r = 0; r < 4; ++r) {
                    const int i = h * 4 + r;
                    const float dotv = (h == 0) ? CA[r] : CB[r];
                    float st3 = sx[i] * cv.x + sy[i] * cv.y + sz[i] * cv.z;
                    float d2  = sq[i] + cv.w - 2.0f * st3;
                    float wgt = exp2f(dotv * k2 - k2);
                    wgt = (d2 < 100.0f) ? wgt : 0.0f;
                    accx[i] = fmaf(wgt, cv.x, accx[i]);
                    accy[i] = fmaf(wgt, cv.y, accy[i]);
                    accz[i] = fmaf(wgt, cv.z, accz[i]);
                    accw[i] += wgt;
                }
            }
        }
        __builtin_amdgcn_s_barrier();
        asm volatile("" ::: "memory");
        cur ^= 1;
    }

    // reduce across the 16 lanes of each group (same n set, different m)
    #pragma unroll
    for (int i = 0; i < 8; ++i) {
        #pragma unroll
        for (int o = 1; o < 16; o <<= 1) {
            accx[i] += __shfl_xor(accx[i], o, 16);
            accy[i] += __shfl_xor(accy[i], o, 16);
            accz[i] += __shfl_xor(accz[i], o, 16);
            accw[i] += __shfl_xor(accw[i], o, 16);
        }
    }
    if (l15 == 0) {
        #pragma unroll
        for (int h = 0; h < 2; ++h) {
            #pragma unroll
            for (int r = 0; r < 4; ++r) {
                int n = n0w + 16 * h + 4 * g + r;
                part[((size_t)split * BB + b) * NN + n] =
                    make_float4(accx[h * 4 + r], accy[h * 4 + r],
                                accz[h * 4 + r], accw[h * 4 + r]);
            }
        }
    }
}

// ---------------------------------------------------------------------------
// Finish: combine splits, normalize, subtract coor_s
// ---------------------------------------------------------------------------
__global__ __launch_bounds__(256) void finish_kernel(const float4* __restrict__ part,
                                                     const float* __restrict__ cs,
                                                     float* __restrict__ out) {
    int idx = blockIdx.x * 256 + threadIdx.x;   // b*NN + n
    if (idx >= BB * NN) return;
    float x = 0.f, y = 0.f, z = 0.f, w = 0.f;
    #pragma unroll
    for (int s = 0; s < NSPLIT; ++s) {
        const float4 v = part[(size_t)s * BB * NN + idx];
        x += v.x; y += v.y; z += v.z; w += v.w;
    }
    const float den = w + 1e-8f;
    out[(size_t)idx * 3 + 0] = x / den - cs[(size_t)idx * 3 + 0];
    out[(size_t)idx * 3 + 1] = y / den - cs[(size_t)idx * 3 + 1];
    out[(size_t)idx * 3 + 2] = z / den - cs[(size_t)idx * 3 + 2];
}

extern "C" void kernel_launch(void* const* d_in, const int* in_sizes, int n_in,
                              void* d_out, int out_size, void* d_ws, size_t ws_size,
                              hipStream_t stream) {
    const float* feat_s = (const float*)d_in[0];
    const float* feat_t = (const float*)d_in[1];
    const float* coor_s = (const float*)d_in[2];
    const float* coor_t = (const float*)d_in[3];
    const float* eps    = (const float*)d_in[4];
    float* out = (float*)d_out;

    // workspace layout: fs2 2MB | ft2 2MB | cs4 128KB | ct4 128KB | part 1MB
    unsigned short* fs2 = (unsigned short*)d_ws;
    unsigned short* ft2 = fs2 + (size_t)BB * NN * 128;
    float4* cs4  = (float4*)(ft2 + (size_t)BB * MM * 128);
    float4* ct4  = cs4 + (size_t)BB * NN;
    float4* part = ct4 + (size_t)BB * MM;

    prep_all<<<FEAT_BLOCKS + COORD_BLOCKS, 256, 0, stream>>>(
        feat_s, feat_t, coor_s, coor_t, fs2, ft2, cs4, ct4);

    flow_mfma<<<dim3(BB * NBLK_B, NSPLIT), 256, 0, stream>>>(
        fs2, ft2, cs4, ct4, eps, part);

    finish_kernel<<<(BB * NN + 255) / 256, 256, 0, stream>>>(part, coor_s, out);
}